// Round 16
// baseline (147.313 us; speedup 1.0000x reference)
//
#include <hip/hip_runtime.h>
#include <cstddef>

// Critic_43104291783486 — round 16: fix the vmcnt-FIFO self-drain + halve
// barrier units.
//  (1) X loads issued BEFORE W loads everywhere: x_write (waits X) no longer
//      FIFO-drains the younger W batch (r15's hidden full-latency-per-step).
//  (2) Super-steps (BK=64): two K-tiles per barrier pair, X double-buffered
//      in LDS, 32 MFMA/unit -> GEMM1 units 24 -> 12.
//  (3) GEMM2: direct-reg W2 B-fragments (r4-verified mapping), per-bounce
//      prefetch, merged 64-col bounces -> units 16 -> 8, no W LDS at all.
// LDS = 10.25KB (X dbuf; slab reuses it). launch_bounds(256,2).
// Unchanged: fp16 MFMA 16x16x32 layouts (r3-r15), grid mapping (FETCH is
// compulsory-minimal since r15), phase2.

#define BN 256
#define HD 256
#define FD 64
#define NHD (BN * HD)
#define XS 40    // X lds row stride (halves)
#define SLS 72   // slab row stride (halves): 144B rows, 16B-aligned

typedef _Float16 f16x8 __attribute__((ext_vector_type(8)));
typedef _Float16 f16x4 __attribute__((ext_vector_type(4)));
typedef float f32x4 __attribute__((ext_vector_type(4)));

#define BAR_LGKM()                                                         \
  asm volatile("s_waitcnt lgkmcnt(0)" ::: "memory");                       \
  __builtin_amdgcn_s_barrier();                                            \
  asm volatile("" ::: "memory");

__device__ __forceinline__ f16x8 pack8(const float v[8]) {
  f16x8 r;
#pragma unroll
  for (int i = 0; i < 8; ++i) r[i] = (_Float16)v[i];
  return r;
}

// ---------- X staging: 64 rows x 32 k fp32 -> regs -> fp16 LDS ----------
__device__ __forceinline__ void x_load(const float* xs0, const float* xs1, int n,
                                       int row0, int kt, int tid, float4 xr[2]) {
  int kOff = kt * 32;
  const float* xs = (kOff < 256) ? xs0 : xs1;   // A-branch: obs then act
  int row = tid >> 2, c = (tid & 3) * 4;
  const float* p = xs + (size_t)(row0 + row) * NHD + n * HD + (kOff & 255) + c;
  xr[0] = *(const float4*)p;
  xr[1] = *(const float4*)(p + 16);
}
__device__ __forceinline__ void x_write(_Float16* Xl, int tid, const float4 xr[2]) {
  int row = tid >> 2, c = (tid & 3) * 4;
  f16x4 a, b;
  a[0] = (_Float16)xr[0].x; a[1] = (_Float16)xr[0].y;
  a[2] = (_Float16)xr[0].z; a[3] = (_Float16)xr[0].w;
  b[0] = (_Float16)xr[1].x; b[1] = (_Float16)xr[1].y;
  b[2] = (_Float16)xr[1].z; b[3] = (_Float16)xr[1].w;
  *(f16x4*)(Xl + row * XS + c) = a;
  *(f16x4*)(Xl + row * XS + c + 16) = b;
}

// ---------- W1 B-fragment batch (r15-verified): 4 frags x 8 dwords ----------
// B-frag elem j (lane l): W[kt*32 + (l>>4)*8 + j][Nbase + nf*16 + (l&15)].
__device__ __forceinline__ void w1_load(const float* __restrict__ wb, float wf[4][8]) {
#pragma unroll
  for (int nf = 0; nf < 4; ++nf)
#pragma unroll
    for (int j = 0; j < 8; ++j) wf[nf][j] = wb[(size_t)j * HD + nf * 16];
}

// ---------- GEMM1 compute: 4 b128 A reads + 16 MFMA (r3-r15 layouts) ----------
__device__ __forceinline__ void g1_compute(const f16x8 b[4], const _Float16* Xl,
                                           int lrow, int lq, f32x4 acc[4][4]) {
#pragma unroll
  for (int m = 0; m < 4; ++m) {
    f16x8 a = *(const f16x8*)(Xl + (m * 16 + lrow) * XS + lq * 8);
#pragma unroll
    for (int nf = 0; nf < 4; ++nf)
      acc[m][nf] = __builtin_amdgcn_mfma_f32_16x16x32_f16(a, b[nf], acc[m][nf], 0, 0, 0);
  }
}

// C1(64x256) = X(64xK) @ W1(Kx256), K = NK*32, NK even. Super-steps of 2 tiles.
template <int NK>
__device__ __forceinline__ void run_gemm1(const float* xs0, const float* xs1,
                                          const float* __restrict__ Wg,
                                          int n, int row0, int tid, int lrow, int lq,
                                          int Nbase, _Float16* Xl0, _Float16* Xl1,
                                          f32x4 acc[4][4]) {
  const float* wb = Wg + (size_t)(lq * 8) * HD + Nbase + lrow;
  float wfA[4][8], wfB[4][8];
  float4 xr0[2], xr1[2];
  // prologue — X first (older), W after (younger): x_write drains X only
  x_load(xs0, xs1, n, row0, 0, tid, xr0);
  x_load(xs0, xs1, n, row0, 1, tid, xr1);
  w1_load(wb, wfA);                              // W[0]
  w1_load(wb + (size_t)32 * HD, wfB);            // W[1]
  x_write(Xl0, tid, xr0);
  x_write(Xl1, tid, xr1);
#pragma unroll 1
  for (int st = 0; st < NK / 2; ++st) {
    BAR_LGKM()                        // X[2st], X[2st+1] published
    f16x8 bA[4], bB[4];               // cvt waits W (issued last super-step)
#pragma unroll
    for (int nf = 0; nf < 4; ++nf) bA[nf] = pack8(wfA[nf]);
#pragma unroll
    for (int nf = 0; nf < 4; ++nf) bB[nf] = pack8(wfB[nf]);
    if (st + 1 < NK / 2) {            // X first, W after (FIFO discipline)
      x_load(xs0, xs1, n, row0, 2 * st + 2, tid, xr0);
      x_load(xs0, xs1, n, row0, 2 * st + 3, tid, xr1);
      w1_load(wb + (size_t)(2 * st + 2) * 32 * HD, wfA);
      w1_load(wb + (size_t)(2 * st + 3) * 32 * HD, wfB);
    }
    g1_compute(bA, Xl0, lrow, lq, acc);           // 32 MFMA + 8 b128 reads
    g1_compute(bB, Xl1, lrow, lq, acc);
    BAR_LGKM()                        // all waves done reading X tiles
    if (st + 1 < NK / 2) {
      x_write(Xl0, tid, xr0);         // waits X only; W stays in flight
      x_write(Xl1, tid, xr1);
    }
  }
}

// ---------- W2 B-fragment batch (r4-verified mapping) ----------
// elem j (lane l): W2[jb*64 + kf*32 + (l>>4)*8 + j][nf*16 + (l&15)].
__device__ __forceinline__ void w2_load(const float* __restrict__ W2g, int jb, int kf,
                                        int lrow, int lq, float wf[4][8]) {
  const float* p = W2g + (size_t)(jb * 64 + kf * 32 + lq * 8) * FD + lrow;
#pragma unroll
  for (int nf = 0; nf < 4; ++nf)
#pragma unroll
    for (int j = 0; j < 8; ++j) wf[nf][j] = p[(size_t)j * FD + nf * 16];
}

// ---------- GEMM2: C2(64x64) += relu(C1+b1) @ W2, 4 merged 64-k bounces ----------
// Bounce jb: writer wave jb publishes its full 64-col h slab [64 rows][64 k];
// all waves: 2 b128 slab reads + 8 reg-W2 frags + 8 MFMA.
__device__ __forceinline__ void gemm2_branch(const f32x4 acc[4][4], f32x4 acc2[4],
                                             const float* __restrict__ W2g,
                                             const float* __restrict__ b1g,
                                             _Float16* slab, int lrow, int lq,
                                             int Nbase, int w) {
  float bv[4];
#pragma unroll
  for (int nf = 0; nf < 4; ++nf) bv[nf] = b1g[Nbase + nf * 16 + lrow];  // L2-hot
  float wf2A[4][8], wf2B[4][8];
  w2_load(W2g, 0, 0, lrow, lq, wf2A);
  w2_load(W2g, 0, 1, lrow, lq, wf2B);
#pragma unroll
  for (int jb = 0; jb < 4; ++jb) {
    if (w == jb) {                    // writer: h = relu(C1+b1), scalar u16 writes
#pragma unroll
      for (int m = 0; m < 4; ++m)
#pragma unroll
        for (int nf = 0; nf < 4; ++nf)
#pragma unroll
          for (int r = 0; r < 4; ++r)
            slab[(m * 16 + lq * 4 + r) * SLS + nf * 16 + lrow] =
                (_Float16)fmaxf(acc[m][nf][r] + bv[nf], 0.f);
    }
    BAR_LGKM()                        // slab published
    f16x8 bbA[4];
#pragma unroll
    for (int nf = 0; nf < 4; ++nf) bbA[nf] = pack8(wf2A[nf]);
    f16x8 a0 = *(const f16x8*)(slab + (w * 16 + lrow) * SLS + lq * 8);
#pragma unroll
    for (int nf = 0; nf < 4; ++nf)
      acc2[nf] = __builtin_amdgcn_mfma_f32_16x16x32_f16(a0, bbA[nf], acc2[nf], 0, 0, 0);
    f16x8 bbB[4];
#pragma unroll
    for (int nf = 0; nf < 4; ++nf) bbB[nf] = pack8(wf2B[nf]);
    if (jb < 3) {                     // prefetch next bounce's W2 frags
      w2_load(W2g, jb + 1, 0, lrow, lq, wf2A);
      w2_load(W2g, jb + 1, 1, lrow, lq, wf2B);
    }
    f16x8 a1 = *(const f16x8*)(slab + (w * 16 + lrow) * SLS + 32 + lq * 8);
#pragma unroll
    for (int nf = 0; nf < 4; ++nf)
      acc2[nf] = __builtin_amdgcn_mfma_f32_16x16x32_f16(a1, bbB[nf], acc2[nf], 0, 0, 0);
    BAR_LGKM()                        // slab reads done before next writer
  }
}

__global__ __launch_bounds__(256, 2) void phase1_kernel(
    const float* __restrict__ obs, const float* __restrict__ act,
    const float* __restrict__ V_W1, const float* __restrict__ V_b1,
    const float* __restrict__ V_W2, const float* __restrict__ V_b2,
    const float* __restrict__ A_W1, const float* __restrict__ A_b1,
    const float* __restrict__ A_W2, const float* __restrict__ A_b2,
    float* __restrict__ Q) {
  // X double-buffer (GEMM1) / h slab (GEMM2) — 10.25KB total, no W LDS at all
  __shared__ __align__(16) _Float16 Xbuf[2 * 64 * XS];
  _Float16* Xl0 = Xbuf;
  _Float16* Xl1 = Xbuf + 64 * XS;
  _Float16* slab = Xbuf;              // 64*SLS = 4608 halves <= 5120 region

  int tid = threadIdx.x;
  int l = tid & 63, w = tid >> 6;
  int lrow = l & 15, lq = l >> 4;
  int Nbase = w * 64;                 // wave owns 64 C1-cols
  int bid = blockIdx.x;
  // node's 4 quarters at stride-8 bids: same XCD, same dispatch round (r15:
  // FETCH = compulsory-minimal with this mapping)
  int n = ((bid >> 5) << 3) | (bid & 7);
  int row0 = ((bid >> 3) & 3) * 64;   // batch quarter

  f32x4 acc[4][4];
  f32x4 acc2[4];
#pragma unroll
  for (int j = 0; j < 4; ++j) acc2[j] = (f32x4){0.f, 0.f, 0.f, 0.f};

  // ---------------- V branch (NK=8 -> 4 super-steps) ----------------
#pragma unroll
  for (int m = 0; m < 4; ++m)
#pragma unroll
    for (int nf = 0; nf < 4; ++nf) acc[m][nf] = (f32x4){0.f, 0.f, 0.f, 0.f};
  run_gemm1<8>(obs, obs, V_W1 + (size_t)n * HD * HD, n, row0, tid, lrow, lq,
               Nbase, Xl0, Xl1, acc);
  gemm2_branch(acc, acc2, V_W2 + (size_t)n * HD * FD, V_b1 + n * HD,
               slab, lrow, lq, Nbase, w);

  // ---------------- A branch (NK=16 -> 8 super-steps) ----------------
#pragma unroll
  for (int m = 0; m < 4; ++m)
#pragma unroll
    for (int nf = 0; nf < 4; ++nf) acc[m][nf] = (f32x4){0.f, 0.f, 0.f, 0.f};
  run_gemm1<16>(obs, act, A_W1 + (size_t)n * 2 * HD * HD, n, row0, tid, lrow, lq,
                Nbase, Xl0, Xl1, acc);
  gemm2_branch(acc, acc2, A_W2 + (size_t)n * HD * FD, A_b1 + n * HD,
               slab, lrow, lq, Nbase, w);

  // ---------------- Q = acc2 + V_b2 + A_b2 ----------------
  const float* vb2 = V_b2 + n * FD;
  const float* ab2 = A_b2 + n * FD;
#pragma unroll
  for (int nf = 0; nf < 4; ++nf) {
    int f = nf * 16 + lrow;
    float bias = vb2[f] + ab2[f];
#pragma unroll
    for (int rr = 0; rr < 4; ++rr) {
      int row = row0 + w * 16 + lq * 4 + rr;
      Q[(size_t)row * (BN * FD) + n * FD + f] = acc2[nf][rr] + bias;
    }
  }
}

// ---------------- phase 2: gather + subset-min + chi + mean ----------------
__global__ __launch_bounds__(256) void phase2_kernel(const float* __restrict__ Q,
                                                     const float* __restrict__ chi_m,
                                                     const int* __restrict__ le,
                                                     float* __restrict__ out) {
  int b = blockIdx.x;
  int n = threadIdx.x;
  // int64-vs-int32 layout hedge: centers = arange(N) => int32 layout has le[5]==1.
  int step = (le[5] == 1) ? 1 : 2;
  const int* e = le + n * 5 * step;
  int c  = e[0 * step] & (BN - 1);
  int n0 = e[1 * step] & (BN - 1);
  int n1 = e[2 * step] & (BN - 1);
  int n2 = e[3 * step] & (BN - 1);
  int n3 = e[4 * step] & (BN - 1);
  const float* ch = chi_m + n * 45;   // (HEADS=3, S=15)
  float cm[15];
#pragma unroll
  for (int s = 0; s < 15; ++s) cm[s] = (ch[s] + ch[15 + s] + ch[30 + s]) * (1.f / 3.f);
  const float* qb = Q + (size_t)b * (BN * FD);
  const float* q0 = qb + n0 * FD;
  const float* q1 = qb + n1 * FD;
  const float* q2 = qb + n2 * FD;
  const float* q3 = qb + n3 * FD;
  const float* qc = qb + c * FD;
  float acc = 0.f;
#pragma unroll
  for (int f = 0; f < FD; f += 4) {
    float4 v0 = *(const float4*)(q0 + f);
    float4 v1 = *(const float4*)(q1 + f);
    float4 v2 = *(const float4*)(q2 + f);
    float4 v3 = *(const float4*)(q3 + f);
    float4 vc = *(const float4*)(qc + f);
    const float* p0 = (const float*)&v0;
    const float* p1 = (const float*)&v1;
    const float* p2 = (const float*)&v2;
    const float* p3 = (const float*)&v3;
    const float* pc = (const float*)&vc;
#pragma unroll
    for (int u = 0; u < 4; ++u) {
      float a = p0[u], bq = p1[u], cq = p2[u], d = p3[u];
      float m01 = fminf(a, bq), m02 = fminf(a, cq), m03 = fminf(a, d);
      float m12 = fminf(bq, cq), m13 = fminf(bq, d), m23 = fminf(cq, d);
      float m012 = fminf(m01, cq), m013 = fminf(m01, d);
      float m023 = fminf(m02, d),  m123 = fminf(m12, d);
      float m0123 = fminf(m01, m23);
      float chi = cm[0] * a   + cm[1] * bq   + cm[2] * m01  + cm[3] * cq
                + cm[4] * m02 + cm[5] * m12  + cm[6] * m012 + cm[7] * d
                + cm[8] * m03 + cm[9] * m13  + cm[10] * m013 + cm[11] * m23
                + cm[12] * m023 + cm[13] * m123 + cm[14] * m0123;
      acc += chi + pc[u];
    }
  }
  out[b * BN + n] = acc * (1.f / 64.f);
}

extern "C" void kernel_launch(void* const* d_in, const int* in_sizes, int n_in,
                              void* d_out, int out_size, void* d_ws, size_t ws_size,
                              hipStream_t stream) {
  (void)in_sizes; (void)n_in; (void)out_size; (void)ws_size;
  const float* obs  = (const float*)d_in[0];
  const float* act  = (const float*)d_in[1];
  const float* V_W1 = (const float*)d_in[2];
  const float* V_b1 = (const float*)d_in[3];
  const float* V_W2 = (const float*)d_in[4];
  const float* V_b2 = (const float*)d_in[5];
  const float* A_W1 = (const float*)d_in[6];
  const float* A_b1 = (const float*)d_in[7];
  const float* A_W2 = (const float*)d_in[8];
  const float* A_b2 = (const float*)d_in[9];
  const float* chim = (const float*)d_in[10];
  const int*   le   = (const int*)d_in[11];
  float* Q   = (float*)d_ws;            // 16 MB scratch: Q[B][N][F]
  float* out = (float*)d_out;

  phase1_kernel<<<dim3(1024), dim3(256), 0, stream>>>(obs, act, V_W1, V_b1, V_W2, V_b2,
                                                      A_W1, A_b1, A_W2, A_b2, Q);
  phase2_kernel<<<dim3(256), dim3(256), 0, stream>>>(Q, chim, le, out);
}

// Round 17
// 140.296 us; speedup vs baseline: 1.0500x; 1.0500x over previous
//
#include <hip/hip_runtime.h>
#include <cstddef>

// Critic_43104291783486 — round 17: BARRIER-FREE K-loop.
// X (obs+act, 64 rows x 512 k) staged to LDS fp16 ONCE per block (64KB) ->
// the 24-tile K-stream has zero barriers and zero LDS writes: per tile each
// wave does 32 W scalar reg-loads (depth-2 named batches, self-paced via its
// own vmcnt deps), 4 cvt-packs, 4 b128 X reads, 16 MFMA. Waves drift freely;
// 8-wave TLP + depth-2 cover latency. Barriers: ~10 total (stage + gemm2).
// LDS 74KB -> 2 blocks/CU. Layouts = r3-r16 verified; gemm2 = r16; phase2 same.

#define BN 256
#define HD 256
#define FD 64
#define NHD (BN * HD)
#define XS2 520  // X lds row stride (halves): 1040B -> A-frag reads 2-way-free
#define SLS 72   // slab row stride (halves)

typedef _Float16 f16x8 __attribute__((ext_vector_type(8)));
typedef _Float16 f16x4 __attribute__((ext_vector_type(4)));
typedef float f32x4 __attribute__((ext_vector_type(4)));

#define BAR_LGKM()                                                         \
  asm volatile("s_waitcnt lgkmcnt(0)" ::: "memory");                       \
  __builtin_amdgcn_s_barrier();                                            \
  asm volatile("" ::: "memory");

__device__ __forceinline__ f16x8 pack8(const float v[8]) {
  f16x8 r;
#pragma unroll
  for (int i = 0; i < 8; ++i) r[i] = (_Float16)v[i];
  return r;
}

// ---------- one-time X stage: 64 rows x 512 k fp32 -> fp16 LDS ----------
// thread t: row = t>>2, quarter q = t&3 (64-float span per source).
__device__ __forceinline__ void stage_load(const float* __restrict__ src, float4 v[8]) {
#pragma unroll
  for (int i = 0; i < 8; ++i) v[i] = *(const float4*)(src + i * 4);
}
__device__ __forceinline__ void stage_commit(_Float16* dst, const float4 v[8]) {
#pragma unroll
  for (int g = 0; g < 4; ++g) {
    f16x8 h;
    h[0] = (_Float16)v[2 * g].x;     h[1] = (_Float16)v[2 * g].y;
    h[2] = (_Float16)v[2 * g].z;     h[3] = (_Float16)v[2 * g].w;
    h[4] = (_Float16)v[2 * g + 1].x; h[5] = (_Float16)v[2 * g + 1].y;
    h[6] = (_Float16)v[2 * g + 1].z; h[7] = (_Float16)v[2 * g + 1].w;
    *(f16x8*)(dst + g * 8) = h;
  }
}

// ---------- W1 B-fragment batch (r15/r16-verified): 4 frags x 8 dwords ----------
// elem j (lane l): W[kt*32 + (l>>4)*8 + j][Nbase + nf*16 + (l&15)].
__device__ __forceinline__ void w1_load(const float* __restrict__ wb, float wf[4][8]) {
#pragma unroll
  for (int nf = 0; nf < 4; ++nf)
#pragma unroll
    for (int j = 0; j < 8; ++j) wf[nf][j] = wb[(size_t)j * HD + nf * 16];
}

// ---------- one K-tile: cvt + prefetch + 4 b128 X reads + 16 MFMA ----------
#define G1_TILE(KT, WFC)                                                     \
  {                                                                          \
    const int kt_ = (KT);                                                    \
    f16x8 bfr[4];            /* waits W[kt] batch (issued at kt-2) */        \
    _Pragma("unroll") for (int nf = 0; nf < 4; ++nf) bfr[nf] = pack8(WFC[nf]); \
    if (kt_ + 2 < NK) w1_load(wb + (size_t)(kt_ + 2) * 32 * HD, WFC);        \
    _Pragma("unroll") for (int m = 0; m < 4; ++m) {                          \
      f16x8 a = *(const f16x8*)(Xl + (m * 16 + lrow) * XS2 + kt_ * 32 + lq * 8); \
      _Pragma("unroll") for (int nf = 0; nf < 4; ++nf)                       \
        acc[m][nf] =                                                         \
            __builtin_amdgcn_mfma_f32_16x16x32_f16(a, bfr[nf], acc[m][nf], 0, 0, 0); \
    }                                                                        \
  }

// C1(64x256) = X(64xK) @ W1(Kx256), K = NK*32, NK even. NO barriers inside.
template <int NK>
__device__ __forceinline__ void run_gemm1(const float* __restrict__ Wg,
                                          int lrow, int lq, int Nbase,
                                          const _Float16* Xl, f32x4 acc[4][4]) {
  const float* wb = Wg + (size_t)(lq * 8) * HD + Nbase + lrow;
  float wfA[4][8], wfB[4][8];
  w1_load(wb, wfA);                              // W[0]
  w1_load(wb + (size_t)32 * HD, wfB);            // W[1]
#pragma unroll 1
  for (int kt = 0; kt < NK; kt += 2) {
    G1_TILE(kt, wfA)
    G1_TILE(kt + 1, wfB)
  }
}

// ---------- W2 B-fragment batch (r4/r16-verified mapping) ----------
__device__ __forceinline__ void w2_load(const float* __restrict__ W2g, int jb, int kf,
                                        int lrow, int lq, float wf[4][8]) {
  const float* p = W2g + (size_t)(jb * 64 + kf * 32 + lq * 8) * FD + lrow;
#pragma unroll
  for (int nf = 0; nf < 4; ++nf)
#pragma unroll
    for (int j = 0; j < 8; ++j) wf[nf][j] = p[(size_t)j * FD + nf * 16];
}

// ---------- GEMM2 (r16): C2(64x64) += relu(C1+b1) @ W2, 4 merged bounces ----------
__device__ __forceinline__ void gemm2_branch(const f32x4 acc[4][4], f32x4 acc2[4],
                                             const float* __restrict__ W2g,
                                             const float* __restrict__ b1g,
                                             _Float16* slab, int lrow, int lq,
                                             int Nbase, int w) {
  float bv[4];
#pragma unroll
  for (int nf = 0; nf < 4; ++nf) bv[nf] = b1g[Nbase + nf * 16 + lrow];  // L2-hot
  float wf2A[4][8], wf2B[4][8];
  w2_load(W2g, 0, 0, lrow, lq, wf2A);
  w2_load(W2g, 0, 1, lrow, lq, wf2B);
#pragma unroll
  for (int jb = 0; jb < 4; ++jb) {
    if (w == jb) {                    // writer publishes its 64-col h slab
#pragma unroll
      for (int m = 0; m < 4; ++m)
#pragma unroll
        for (int nf = 0; nf < 4; ++nf)
#pragma unroll
          for (int r = 0; r < 4; ++r)
            slab[(m * 16 + lq * 4 + r) * SLS + nf * 16 + lrow] =
                (_Float16)fmaxf(acc[m][nf][r] + bv[nf], 0.f);
    }
    BAR_LGKM()                        // slab published (syncs drifted waves)
    f16x8 bbA[4];
#pragma unroll
    for (int nf = 0; nf < 4; ++nf) bbA[nf] = pack8(wf2A[nf]);
    f16x8 a0 = *(const f16x8*)(slab + (w * 16 + lrow) * SLS + lq * 8);
#pragma unroll
    for (int nf = 0; nf < 4; ++nf)
      acc2[nf] = __builtin_amdgcn_mfma_f32_16x16x32_f16(a0, bbA[nf], acc2[nf], 0, 0, 0);
    f16x8 bbB[4];
#pragma unroll
    for (int nf = 0; nf < 4; ++nf) bbB[nf] = pack8(wf2B[nf]);
    if (jb < 3) {                     // prefetch next bounce's W2 frags
      w2_load(W2g, jb + 1, 0, lrow, lq, wf2A);
      w2_load(W2g, jb + 1, 1, lrow, lq, wf2B);
    }
    f16x8 a1 = *(const f16x8*)(slab + (w * 16 + lrow) * SLS + 32 + lq * 8);
#pragma unroll
    for (int nf = 0; nf < 4; ++nf)
      acc2[nf] = __builtin_amdgcn_mfma_f32_16x16x32_f16(a1, bbB[nf], acc2[nf], 0, 0, 0);
    BAR_LGKM()                        // reads done before next writer
  }
}

__global__ __launch_bounds__(256, 2) void phase1_kernel(
    const float* __restrict__ obs, const float* __restrict__ act,
    const float* __restrict__ V_W1, const float* __restrict__ V_b1,
    const float* __restrict__ V_W2, const float* __restrict__ V_b2,
    const float* __restrict__ A_W1, const float* __restrict__ A_b1,
    const float* __restrict__ A_W2, const float* __restrict__ A_b2,
    float* __restrict__ Q) {
  // X [64][XS2] (65KB, persistent) + slab [64][SLS] (9KB) = 74KB -> 2 blocks/CU
  __shared__ __align__(16) _Float16 Xl[64 * XS2];
  __shared__ __align__(16) _Float16 slab[64 * SLS];

  int tid = threadIdx.x;
  int l = tid & 63, w = tid >> 6;
  int lrow = l & 15, lq = l >> 4;
  int Nbase = w * 64;                 // wave owns 64 C1-cols
  int bid = blockIdx.x;
  // node's 4 quarters at stride-8 bids: same XCD, same dispatch round
  int n = ((bid >> 5) << 3) | (bid & 7);
  int row0 = ((bid >> 3) & 3) * 64;   // batch quarter

  // ---------------- one-time X stage: obs -> k 0..255, act -> k 256..511 ----
  {
    int row = tid >> 2, q = tid & 3;
    const float* po = obs + (size_t)(row0 + row) * NHD + n * HD + q * 64;
    const float* pa = act + (size_t)(row0 + row) * NHD + n * HD + q * 64;
    _Float16* xd = Xl + row * XS2 + q * 64;
    float4 c0[8], c1[8], c2[8], c3[8];
    stage_load(po, c0);
    stage_load(po + 32, c1);
    stage_load(pa, c2);
    stage_load(pa + 32, c3);
    stage_commit(xd, c0);
    stage_commit(xd + 32, c1);
    stage_commit(xd + 256, c2);
    stage_commit(xd + 288, c3);
  }
  BAR_LGKM()                          // X published once; no K-loop barriers

  f32x4 acc[4][4];
  f32x4 acc2[4];
#pragma unroll
  for (int j = 0; j < 4; ++j) acc2[j] = (f32x4){0.f, 0.f, 0.f, 0.f};

  // ---------------- V branch (NK=8, X cols 0..255) ----------------
#pragma unroll
  for (int m = 0; m < 4; ++m)
#pragma unroll
    for (int nf = 0; nf < 4; ++nf) acc[m][nf] = (f32x4){0.f, 0.f, 0.f, 0.f};
  run_gemm1<8>(V_W1 + (size_t)n * HD * HD, lrow, lq, Nbase, Xl, acc);
  gemm2_branch(acc, acc2, V_W2 + (size_t)n * HD * FD, V_b1 + n * HD,
               slab, lrow, lq, Nbase, w);

  // ---------------- A branch (NK=16, X cols 0..511) ----------------
#pragma unroll
  for (int m = 0; m < 4; ++m)
#pragma unroll
    for (int nf = 0; nf < 4; ++nf) acc[m][nf] = (f32x4){0.f, 0.f, 0.f, 0.f};
  run_gemm1<16>(A_W1 + (size_t)n * 2 * HD * HD, lrow, lq, Nbase, Xl, acc);
  gemm2_branch(acc, acc2, A_W2 + (size_t)n * HD * FD, A_b1 + n * HD,
               slab, lrow, lq, Nbase, w);

  // ---------------- Q = acc2 + V_b2 + A_b2 ----------------
  const float* vb2 = V_b2 + n * FD;
  const float* ab2 = A_b2 + n * FD;
#pragma unroll
  for (int nf = 0; nf < 4; ++nf) {
    int f = nf * 16 + lrow;
    float bias = vb2[f] + ab2[f];
#pragma unroll
    for (int rr = 0; rr < 4; ++rr) {
      int row = row0 + w * 16 + lq * 4 + rr;
      Q[(size_t)row * (BN * FD) + n * FD + f] = acc2[nf][rr] + bias;
    }
  }
}

// ---------------- phase 2: gather + subset-min + chi + mean ----------------
__global__ __launch_bounds__(256) void phase2_kernel(const float* __restrict__ Q,
                                                     const float* __restrict__ chi_m,
                                                     const int* __restrict__ le,
                                                     float* __restrict__ out) {
  int b = blockIdx.x;
  int n = threadIdx.x;
  // int64-vs-int32 layout hedge: centers = arange(N) => int32 layout has le[5]==1.
  int step = (le[5] == 1) ? 1 : 2;
  const int* e = le + n * 5 * step;
  int c  = e[0 * step] & (BN - 1);
  int n0 = e[1 * step] & (BN - 1);
  int n1 = e[2 * step] & (BN - 1);
  int n2 = e[3 * step] & (BN - 1);
  int n3 = e[4 * step] & (BN - 1);
  const float* ch = chi_m + n * 45;   // (HEADS=3, S=15)
  float cm[15];
#pragma unroll
  for (int s = 0; s < 15; ++s) cm[s] = (ch[s] + ch[15 + s] + ch[30 + s]) * (1.f / 3.f);
  const float* qb = Q + (size_t)b * (BN * FD);
  const float* q0 = qb + n0 * FD;
  const float* q1 = qb + n1 * FD;
  const float* q2 = qb + n2 * FD;
  const float* q3 = qb + n3 * FD;
  const float* qc = qb + c * FD;
  float acc = 0.f;
#pragma unroll
  for (int f = 0; f < FD; f += 4) {
    float4 v0 = *(const float4*)(q0 + f);
    float4 v1 = *(const float4*)(q1 + f);
    float4 v2 = *(const float4*)(q2 + f);
    float4 v3 = *(const float4*)(q3 + f);
    float4 vc = *(const float4*)(qc + f);
    const float* p0 = (const float*)&v0;
    const float* p1 = (const float*)&v1;
    const float* p2 = (const float*)&v2;
    const float* p3 = (const float*)&v3;
    const float* pc = (const float*)&vc;
#pragma unroll
    for (int u = 0; u < 4; ++u) {
      float a = p0[u], bq = p1[u], cq = p2[u], d = p3[u];
      float m01 = fminf(a, bq), m02 = fminf(a, cq), m03 = fminf(a, d);
      float m12 = fminf(bq, cq), m13 = fminf(bq, d), m23 = fminf(cq, d);
      float m012 = fminf(m01, cq), m013 = fminf(m01, d);
      float m023 = fminf(m02, d),  m123 = fminf(m12, d);
      float m0123 = fminf(m01, m23);
      float chi = cm[0] * a   + cm[1] * bq   + cm[2] * m01  + cm[3] * cq
                + cm[4] * m02 + cm[5] * m12  + cm[6] * m012 + cm[7] * d
                + cm[8] * m03 + cm[9] * m13  + cm[10] * m013 + cm[11] * m23
                + cm[12] * m023 + cm[13] * m123 + cm[14] * m0123;
      acc += chi + pc[u];
    }
  }
  out[b * BN + n] = acc * (1.f / 64.f);
}

extern "C" void kernel_launch(void* const* d_in, const int* in_sizes, int n_in,
                              void* d_out, int out_size, void* d_ws, size_t ws_size,
                              hipStream_t stream) {
  (void)in_sizes; (void)n_in; (void)out_size; (void)ws_size;
  const float* obs  = (const float*)d_in[0];
  const float* act  = (const float*)d_in[1];
  const float* V_W1 = (const float*)d_in[2];
  const float* V_b1 = (const float*)d_in[3];
  const float* V_W2 = (const float*)d_in[4];
  const float* V_b2 = (const float*)d_in[5];
  const float* A_W1 = (const float*)d_in[6];
  const float* A_b1 = (const float*)d_in[7];
  const float* A_W2 = (const float*)d_in[8];
  const float* A_b2 = (const float*)d_in[9];
  const float* chim = (const float*)d_in[10];
  const int*   le   = (const int*)d_in[11];
  float* Q   = (float*)d_ws;            // 16 MB scratch: Q[B][N][F]
  float* out = (float*)d_out;

  phase1_kernel<<<dim3(1024), dim3(256), 0, stream>>>(obs, act, V_W1, V_b1, V_W2, V_b2,
                                                      A_W1, A_b1, A_W2, A_b2, Q);
  phase2_kernel<<<dim3(256), dim3(256), 0, stream>>>(Q, chim, le, out);
}